// Round 18
// baseline (41727.234 us; speedup 1.0000x reference)
//
#include <hip/hip_runtime.h>
#include <stdint.h>

// ---------------- problem constants ----------------
#define TN     2048     // time steps
#define NBLK   192      // 4 groups x (16 A-blocks + 32 B-blocks)

// LDS layout (pad strides == 6 mod 32 words -> ~2-way bank aliasing, free):
#define ASTRIDE  524
#define B0STRIDE 1036
#define BSTRIDE  524
#define R1BASE   33152          // 32*1036
#define R2BASE   41536          // R1BASE + 16*524
#define EXCH_OFF  100608
#define SX_OFF    109312
#define FMISC_OFF 113408
#define SMEM_BYTES 114688

// ws layout:
//   0       : h0x bf16 [4 slots][256][512]   (1 MiB)   slot(t)=t&3; t=-1 -> slot 3
//   1048576 : h1x bf16 [4 slots][256][512]   (1 MiB)
//   2097152 : counters u32[256]; group g: prodA at g*64, prodB at g*64+32
#define H0_OFF  0
#define H1_OFF  1048576
#define CNT_OFF 2097152

typedef __attribute__((ext_vector_type(8))) short bf16x8;
typedef __attribute__((ext_vector_type(4))) float f32x4;

__device__ __forceinline__ float sigf(float v)   { return 1.0f / (1.0f + __expf(-v)); }
__device__ __forceinline__ float tanhf_(float v) { return 2.0f / (1.0f + __expf(-2.0f * v)) - 1.0f; }
__device__ __forceinline__ unsigned short f2bf(float f) {
  unsigned u = __float_as_uint(f);
  u += 0x7fffu + ((u >> 16) & 1u);   // RNE
  return (unsigned short)(u >> 16);
}

// Agent-scope (IF coherence point) 16B fragment load -- proven R6-R17.
__device__ __forceinline__ bf16x8 ld_coh16(const unsigned short* p) {
  union { unsigned long long q[2]; bf16x8 v; } u;
  u.q[0] = __hip_atomic_load((const unsigned long long*)p,
                             __ATOMIC_RELAXED, __HIP_MEMORY_SCOPE_AGENT);
  u.q[1] = __hip_atomic_load((const unsigned long long*)p + 1,
                             __ATOMIC_RELAXED, __HIP_MEMORY_SCOPE_AGENT);
  return u.v;
}

// Re-run safe init: state mirrors (slot 3), out = b_out, counters = 0.
extern "C" __global__ void gru_init(const float* __restrict__ h0,
                                    const float* __restrict__ h1,
                                    const float* __restrict__ b_out,
                                    float* __restrict__ out,
                                    char* __restrict__ ws) {
  int i = blockIdx.x * 256 + threadIdx.x;     // 512 blocks
  unsigned short* h0x = (unsigned short*)(ws + H0_OFF);
  unsigned short* h1x = (unsigned short*)(ws + H1_OFF);
  h0x[3 * 131072 + i] = f2bf(h0[i]);
  h1x[3 * 131072 + i] = f2bf(h1[i]);
  if (blockIdx.x == 0) out[threadIdx.x] = b_out[0];
  if (blockIdx.x == 1) ((unsigned*)(ws + CNT_OFF))[threadIdx.x] = 0u;
}

extern "C" __global__ void __launch_bounds__(256, 1)
gru_main(const float* __restrict__ x,
         const float* __restrict__ W_ih1, const float* __restrict__ W_hh1,
         const float* __restrict__ b_ih1, const float* __restrict__ b_hh1,
         const float* __restrict__ W_ih2, const float* __restrict__ W_hh2,
         const float* __restrict__ b_ih2, const float* __restrict__ b_hh2,
         const float* __restrict__ W_out, const float* __restrict__ b_out,
         const float* __restrict__ h0in, const float* __restrict__ h1in,
         float* __restrict__ out, char* __restrict__ ws)
{
  extern __shared__ char smem[];
  unsigned short* wlds = (unsigned short*)smem;
  float* exch  = (float*)(smem + EXCH_OFF);
  unsigned short* sxu = (unsigned short*)(smem + SX_OFF);
  float* fmisc = (float*)(smem + FMISC_OFF);

  unsigned short* h0x = (unsigned short*)(ws + H0_OFF);
  unsigned short* h1x = (unsigned short*)(ws + H1_OFF);

  const int bid = blockIdx.x, tid = threadIdx.x;
  const int w = tid >> 6, l = tid & 63, l15 = l & 15, l4 = l >> 4;
  const int p_ = w >> 1;     // M half: rows 0-31 / 32-63 of the 64-row batch tile
  const int hh = w & 1;      // A: column half; B: gate role (r,in_ / z,hn)

  // group mapping, XCD-aware: blocks bid%8 in {2g,2g+1} form group g
  const int bt  = (bid & 7) >> 1;                 // group = batch tile
  const int sub = (bid >> 3) * 2 + (bid & 1);     // 0..47 within group
  const bool isA = (sub < 16);
  const int S = isA ? sub * 32 : (sub - 16) * 16;

  unsigned* pA = (unsigned*)(ws + CNT_OFF) + bt * 64;
  unsigned* pB = pA + 32;

  // ---------------- weight preload into LDS (bf16) ----------------
  if (isA) {
    for (int idx = tid; idx < 96 * 512; idx += 256) {
      int j = idx >> 9, kk = idx & 511;
      int h = j / 48, rr = j % 48, g = rr >> 4, c2 = rr & 15;
      int grow = g * 512 + S + h * 16 + c2;
      wlds[j * ASTRIDE + kk] = f2bf(W_hh1[grow * 512 + kk]);
    }
    if (tid < 96) {
      int j = tid, h = j / 48, rr = j % 48, g = rr >> 4, c2 = rr & 15;
      int grow = g * 512 + S + h * 16 + c2;
      fmisc[j]       = W_ih1[grow];
      fmisc[96 + j]  = b_ih1[grow];
      fmisc[192 + j] = b_hh1[grow];
    }
  } else {
    // region0: rows 0..15 = r-gate, 16..31 = z-gate; K=1024 = [W_ih2 | W_hh2]
    for (int idx = tid; idx < 32 * 1024; idx += 256) {
      int j = idx >> 10, kk = idx & 1023;
      int g = j >> 4, c2 = S + (j & 15);
      float v = (kk < 512) ? W_ih2[(g * 512 + c2) * 512 + kk]
                           : W_hh2[(g * 512 + c2) * 512 + kk - 512];
      wlds[j * B0STRIDE + kk] = f2bf(v);
    }
    // region1: in_ rows (W_ih2 n-gate); region2: hn rows (W_hh2 n-gate); K=512
    for (int idx = tid; idx < 16 * 512; idx += 256) {
      int j2 = idx >> 9, kk = idx & 511;
      wlds[R1BASE + j2 * BSTRIDE + kk] = f2bf(W_ih2[(1024 + S + j2) * 512 + kk]);
      wlds[R2BASE + j2 * BSTRIDE + kk] = f2bf(W_hh2[(1024 + S + j2) * 512 + kk]);
    }
    if (tid < 48) {
      int g = tid >> 4, c2 = S + (tid & 15);
      fmisc[tid]      = b_ih2[g * 512 + c2];
      fmisc[48 + tid] = b_hh2[g * 512 + c2];
    }
  }
  __syncthreads();

  // ---------------- per-thread constants / carries ----------------
  int rowb[2][4];
  int arowOff[2];
  #pragma unroll
  for (int mtl = 0; mtl < 2; ++mtl) {
    arowOff[mtl] = ((p_ * 2 + mtl) * 16 + l15) * 512;     // A-fragment row (lane&15-based)
    #pragma unroll
    for (int q = 0; q < 4; ++q)
      rowb[mtl][q] = bt * 64 + (p_ * 2 + mtl) * 16 + l4 * 4 + q;  // D row (reg-based)
  }

  float carry[2][4];
  #pragma unroll
  for (int mtl = 0; mtl < 2; ++mtl)
    #pragma unroll
    for (int q = 0; q < 4; ++q) carry[mtl][q] = 0.0f;
  if (isA) {
    int c = S + hh * 16 + l15;
    #pragma unroll
    for (int mtl = 0; mtl < 2; ++mtl)
      #pragma unroll
      for (int q = 0; q < 4; ++q) carry[mtl][q] = h0in[rowb[mtl][q] * 512 + c];
  } else if (hh == 1) {
    int c = S + l15;
    #pragma unroll
    for (int mtl = 0; mtl < 2; ++mtl)
      #pragma unroll
      for (int q = 0; q < 4; ++q) carry[mtl][q] = h1in[rowb[mtl][q] * 512 + c];
  }
  const float wout = (!isA && hh == 1) ? W_out[S + l15] : 0.0f;

  int dead = 0;   // only tid0's copy matters

  // wait until *c0 >= t0 && *c1 >= t1 (tid0 polls relaxed/sc1).
  // BACKOFF polling: one immediate fast-path check, then ~1.5K-cycle sleeps.
  auto block_wait = [&](unsigned* c0, unsigned t0, unsigned* c1, unsigned t1) {
    if (tid == 0 && !dead) {
      if (__hip_atomic_load(c0, __ATOMIC_RELAXED, __HIP_MEMORY_SCOPE_AGENT) < t0 ||
          __hip_atomic_load(c1, __ATOMIC_RELAXED, __HIP_MEMORY_SCOPE_AGENT) < t1) {
        int spins = 0;
        for (;;) {
          __builtin_amdgcn_s_sleep(24);   // backoff FIRST, then re-check
          if (__hip_atomic_load(c0, __ATOMIC_RELAXED, __HIP_MEMORY_SCOPE_AGENT) >= t0 &&
              __hip_atomic_load(c1, __ATOMIC_RELAXED, __HIP_MEMORY_SCOPE_AGENT) >= t1) break;
          if (++spins > 30000) { dead = 1; break; }   // bounded failure, no hang
        }
      }
    }
    __syncthreads();
  };
  // publisher: all state stores are sc1 write-through; drain them, then relaxed add
  auto block_publish = [&](unsigned* c) {
    asm volatile("s_waitcnt vmcnt(0)" ::: "memory");
    __syncthreads();
    if (tid == 0) __hip_atomic_fetch_add(c, 1u, __ATOMIC_RELAXED, __HIP_MEMORY_SCOPE_AGENT);
  };
  // coherent (IF-level, sc1) u64 store of repacked state
  auto st_coh = [&](unsigned short* p, unsigned long long v) {
    __hip_atomic_store((unsigned long long*)p, v, __ATOMIC_RELAXED, __HIP_MEMORY_SCOPE_AGENT);
  };

  if (isA) {
    // ============ cell-1 blocks: compute h0(k), k = 0..TN-1 ============
    for (int k = 0; k < TN; ++k) {
      // x column loads are flag-independent: issue before the wait
      float xv[2][4];
      #pragma unroll
      for (int mtl = 0; mtl < 2; ++mtl)
        #pragma unroll
        for (int q = 0; q < 4; ++q) xv[mtl][q] = x[rowb[mtl][q] * 2048 + k];

      block_wait(pA, 16u * (unsigned)k,
                 pB, (k >= 3) ? 32u * (unsigned)(k - 3) : 0u);

      f32x4 acc[2][3];
      #pragma unroll
      for (int mtl = 0; mtl < 2; ++mtl)
        #pragma unroll
        for (int g = 0; g < 3; ++g) acc[mtl][g] = f32x4{0.f, 0.f, 0.f, 0.f};

      const unsigned short* srcA = h0x + ((k + 3) & 3) * 131072 + bt * 32768; // h0(k-1)
      #pragma unroll 4
      for (int ks = 0; ks < 16; ++ks) {
        bf16x8 af[2];
        #pragma unroll
        for (int mtl = 0; mtl < 2; ++mtl)
          af[mtl] = ld_coh16(srcA + arowOff[mtl] + ks * 32 + l4 * 8);
        #pragma unroll
        for (int g = 0; g < 3; ++g) {
          bf16x8 bw = *(const bf16x8*)(wlds + (hh * 48 + g * 16 + l15) * ASTRIDE + ks * 32 + l4 * 8);
          #pragma unroll
          for (int mtl = 0; mtl < 2; ++mtl)
            acc[mtl][g] = __builtin_amdgcn_mfma_f32_16x16x32_bf16(af[mtl], bw, acc[mtl][g], 0, 0, 0);
        }
      }

      int cc = hh * 16 + l15;          // local column 0..31
      int jb = hh * 48 + l15;
      float wir = fmisc[jb],       wiz = fmisc[jb + 16],       win = fmisc[jb + 32];
      float bir = fmisc[96 + jb],  biz = fmisc[96 + jb + 16],  bin = fmisc[96 + jb + 32];
      float bhr = fmisc[192 + jb], bhz = fmisc[192 + jb + 16], bhn = fmisc[192 + jb + 32];
      #pragma unroll
      for (int mtl = 0; mtl < 2; ++mtl)
        #pragma unroll
        for (int q = 0; q < 4; ++q) {
          float rg = sigf(xv[mtl][q] * wir + bir + acc[mtl][0][q] + bhr);
          float zg = sigf(xv[mtl][q] * wiz + biz + acc[mtl][1][q] + bhz);
          float ng = tanhf_(xv[mtl][q] * win + bin + rg * (acc[mtl][2][q] + bhn));
          float hv = (1.0f - zg) * ng + zg * carry[mtl][q];
          carry[mtl][q] = hv;
          sxu[((p_ * 2 + mtl) * 16 + l4 * 4 + q) * 32 + cc] = f2bf(hv);  // repack
        }
      __syncthreads();
      {
        const unsigned long long* sxq = (const unsigned long long*)sxu;
        unsigned long long v0 = sxq[tid * 2], v1 = sxq[tid * 2 + 1];
        unsigned short* dsth = h0x + (k & 3) * 131072
                             + (bt * 64 + (tid >> 2)) * 512 + S + (tid & 3) * 8;
        st_coh(dsth, v0);
        st_coh(dsth + 4, v1);
      }
      block_publish(pA);
    }
  } else {
    // ============ cell-2 blocks: compute h1(j), j = 0..TN-1 ============
    // R17 phase order (old data first) + R18: each half's 32 fragment loads
    // batch-issued into registers BEFORE the MFMA sweep -> one exposed
    // IF-latency window per half instead of ~4 partially-exposed ones.
    for (int j = 0; j < TN; ++j) {
      f32x4 acc[2][2];
      #pragma unroll
      for (int mtl = 0; mtl < 2; ++mtl)
        #pragma unroll
        for (int g = 0; g < 2; ++g) acc[mtl][g] = f32x4{0.f, 0.f, 0.f, 0.f};

      // ---- phase 1: h0(j) half (K 0..511) -- needs pA >= 16(j+1) [usually instant] ----
      block_wait(pA, 16u * (unsigned)(j + 1), pA, 0u);

      const unsigned short* src0 = h0x + (j & 3) * 131072 + bt * 32768;       // h0(j)
      {
        bf16x8 fr0[2][16];
        #pragma unroll
        for (int ks = 0; ks < 16; ++ks)
          #pragma unroll
          for (int mtl = 0; mtl < 2; ++mtl)
            fr0[mtl][ks] = ld_coh16(src0 + arowOff[mtl] + ks * 32 + l4 * 8);

        #pragma unroll
        for (int ks = 0; ks < 16; ++ks) {
          bf16x8 b0 = *(const bf16x8*)(wlds + (hh * 16 + l15) * B0STRIDE + ks * 32 + l4 * 8);
          #pragma unroll
          for (int mtl = 0; mtl < 2; ++mtl)
            acc[mtl][0] = __builtin_amdgcn_mfma_f32_16x16x32_bf16(fr0[mtl][ks], b0, acc[mtl][0], 0, 0, 0);
          if (hh == 0) {
            bf16x8 b1 = *(const bf16x8*)(wlds + R1BASE + l15 * BSTRIDE + ks * 32 + l4 * 8);
            #pragma unroll
            for (int mtl = 0; mtl < 2; ++mtl)
              acc[mtl][1] = __builtin_amdgcn_mfma_f32_16x16x32_bf16(fr0[mtl][ks], b1, acc[mtl][1], 0, 0, 0);
          }
        }
      }

      // ---- phase 2: h1(j-1) half (K 512..1023) -- needs pB >= 32j (visibility hidden) ----
      block_wait(pB, 32u * (unsigned)j, pB, 0u);

      const unsigned short* src1 = h1x + ((j + 3) & 3) * 131072 + bt * 32768; // h1(j-1)
      {
        bf16x8 fr1[2][16];
        #pragma unroll
        for (int c = 0; c < 16; ++c)
          #pragma unroll
          for (int mtl = 0; mtl < 2; ++mtl)
            fr1[mtl][c] = ld_coh16(src1 + arowOff[mtl] + c * 32 + l4 * 8);

        #pragma unroll
        for (int ks = 16; ks < 32; ++ks) {
          int c = ks - 16;
          bf16x8 b0 = *(const bf16x8*)(wlds + (hh * 16 + l15) * B0STRIDE + ks * 32 + l4 * 8);
          #pragma unroll
          for (int mtl = 0; mtl < 2; ++mtl)
            acc[mtl][0] = __builtin_amdgcn_mfma_f32_16x16x32_bf16(fr1[mtl][c], b0, acc[mtl][0], 0, 0, 0);
          if (hh == 1) {
            bf16x8 b1 = *(const bf16x8*)(wlds + R2BASE + l15 * BSTRIDE + c * 32 + l4 * 8);
            #pragma unroll
            for (int mtl = 0; mtl < 2; ++mtl)
              acc[mtl][1] = __builtin_amdgcn_mfma_f32_16x16x32_bf16(fr1[mtl][c], b1, acc[mtl][1], 0, 0, 0);
          }
        }
      }

      // exchange r/in_ (hh0) -> hh1 waves
      if (hh == 0) {
        #pragma unroll
        for (int mtl = 0; mtl < 2; ++mtl)
          #pragma unroll
          for (int qn = 0; qn < 2; ++qn)
            #pragma unroll
            for (int q = 0; q < 4; ++q)
              exch[((p_ * 2 + qn) * 32 + mtl * 16 + l4 * 4 + q) * 17 + l15] = acc[mtl][qn][q];
      }
      __syncthreads();
      if (hh == 1) {
        float bir = fmisc[l15],      biz = fmisc[16 + l15], bin = fmisc[32 + l15];
        float bhr = fmisc[48 + l15], bhz = fmisc[64 + l15], bhn = fmisc[80 + l15];
        #pragma unroll
        for (int mtl = 0; mtl < 2; ++mtl)
          #pragma unroll
          for (int q = 0; q < 4; ++q) {
            float rv = exch[((p_ * 2 + 0) * 32 + mtl * 16 + l4 * 4 + q) * 17 + l15];
            float iv = exch[((p_ * 2 + 1) * 32 + mtl * 16 + l4 * 4 + q) * 17 + l15];
            float rg = sigf(rv + bir + bhr);
            float zg = sigf(acc[mtl][0][q] + biz + bhz);
            float ng = tanhf_(iv + bin + rg * (acc[mtl][1][q] + bhn));
            float hv = (1.0f - zg) * ng + zg * carry[mtl][q];
            carry[mtl][q] = hv;
            sxu[((p_ * 2 + mtl) * 16 + l4 * 4 + q) * 16 + l15] = f2bf(hv);  // repack
            if (j == TN - 1) atomicAdd(&out[rowb[mtl][q]], hv * wout);      // projection
          }
      }
      __syncthreads();
      {
        const unsigned long long* sxq = (const unsigned long long*)sxu;
        unsigned long long v = sxq[tid];
        unsigned short* dsth = h1x + (j & 3) * 131072
                             + (bt * 64 + (tid >> 2)) * 512 + S + (tid & 3) * 4;
        st_coh(dsth, v);
      }
      block_publish(pB);
    }
  }
}

extern "C" void kernel_launch(void* const* d_in, const int* in_sizes, int n_in,
                              void* d_out, int out_size, void* d_ws, size_t ws_size,
                              hipStream_t stream) {
  const float* x     = (const float*)d_in[0];
  const float* h0in  = (const float*)d_in[1];
  const float* h1in  = (const float*)d_in[2];
  const float* W_ih1 = (const float*)d_in[3];
  const float* W_hh1 = (const float*)d_in[4];
  const float* b_ih1 = (const float*)d_in[5];
  const float* b_hh1 = (const float*)d_in[6];
  const float* W_ih2 = (const float*)d_in[7];
  const float* W_hh2 = (const float*)d_in[8];
  const float* b_ih2 = (const float*)d_in[9];
  const float* b_hh2 = (const float*)d_in[10];
  const float* W_out = (const float*)d_in[11];
  const float* b_out = (const float*)d_in[12];
  float* out = (float*)d_out;
  char* ws = (char*)d_ws;

  (void)in_sizes; (void)n_in; (void)out_size; (void)ws_size;

  hipFuncSetAttribute((const void*)gru_main,
                      hipFuncAttributeMaxDynamicSharedMemorySize, SMEM_BYTES);

  hipLaunchKernelGGL(gru_init, dim3(512), dim3(256), 0, stream,
                     h0in, h1in, b_out, out, ws);

  void* args[] = { (void*)&x,
                   (void*)&W_ih1, (void*)&W_hh1, (void*)&b_ih1, (void*)&b_hh1,
                   (void*)&W_ih2, (void*)&W_hh2, (void*)&b_ih2, (void*)&b_hh2,
                   (void*)&W_out, (void*)&b_out,
                   (void*)&h0in, (void*)&h1in,
                   (void*)&out, (void*)&ws };
  hipLaunchCooperativeKernel((const void*)gru_main, dim3(NBLK), dim3(256),
                             args, SMEM_BYTES, stream);
}

// Round 19
// 34718.005 us; speedup vs baseline: 1.2019x; 1.2019x over previous
//
#include <hip/hip_runtime.h>
#include <stdint.h>

// ---------------- problem constants ----------------
#define TN     2048     // time steps
#define NBLK   192      // 4 groups x (16 A-blocks + 32 B-blocks)

// LDS layout (pad strides == 6 mod 32 words -> ~2-way bank aliasing, free):
#define ASTRIDE  524
#define B0STRIDE 1036
#define BSTRIDE  524
#define R1BASE   33152          // 32*1036
#define R2BASE   41536          // R1BASE + 16*524
#define EXCH_OFF  100608
#define SX_OFF    109312
#define FMISC_OFF 113408
#define SMEM_BYTES 114688

// ws layout:
//   0       : h0x bf16 [4 slots][256][512]   (1 MiB)   slot(t)=t&3; t=-1 -> slot 3
//   1048576 : h1x bf16 [4 slots][256][512]   (1 MiB)
//   2097152 : counters u32[256]; group g: prodA at g*64, prodB at g*64+32
#define H0_OFF  0
#define H1_OFF  1048576
#define CNT_OFF 2097152

typedef __attribute__((ext_vector_type(8))) short bf16x8;
typedef __attribute__((ext_vector_type(4))) float f32x4;

__device__ __forceinline__ float sigf(float v)   { return 1.0f / (1.0f + __expf(-v)); }
__device__ __forceinline__ float tanhf_(float v) { return 2.0f / (1.0f + __expf(-2.0f * v)) - 1.0f; }
__device__ __forceinline__ unsigned short f2bf(float f) {
  unsigned u = __float_as_uint(f);
  u += 0x7fffu + ((u >> 16) & 1u);   // RNE
  return (unsigned short)(u >> 16);
}

// Agent-scope (IF coherence point) 16B fragment load -- proven R6-R17.
__device__ __forceinline__ bf16x8 ld_coh16(const unsigned short* p) {
  union { unsigned long long q[2]; bf16x8 v; } u;
  u.q[0] = __hip_atomic_load((const unsigned long long*)p,
                             __ATOMIC_RELAXED, __HIP_MEMORY_SCOPE_AGENT);
  u.q[1] = __hip_atomic_load((const unsigned long long*)p + 1,
                             __ATOMIC_RELAXED, __HIP_MEMORY_SCOPE_AGENT);
  return u.v;
}

// Re-run safe init: state mirrors (slot 3), out = b_out, counters = 0.
extern "C" __global__ void gru_init(const float* __restrict__ h0,
                                    const float* __restrict__ h1,
                                    const float* __restrict__ b_out,
                                    float* __restrict__ out,
                                    char* __restrict__ ws) {
  int i = blockIdx.x * 256 + threadIdx.x;     // 512 blocks
  unsigned short* h0x = (unsigned short*)(ws + H0_OFF);
  unsigned short* h1x = (unsigned short*)(ws + H1_OFF);
  h0x[3 * 131072 + i] = f2bf(h0[i]);
  h1x[3 * 131072 + i] = f2bf(h1[i]);
  if (blockIdx.x == 0) out[threadIdx.x] = b_out[0];
  if (blockIdx.x == 1) ((unsigned*)(ws + CNT_OFF))[threadIdx.x] = 0u;
}

extern "C" __global__ void __launch_bounds__(256, 1)
gru_main(const float* __restrict__ x,
         const float* __restrict__ W_ih1, const float* __restrict__ W_hh1,
         const float* __restrict__ b_ih1, const float* __restrict__ b_hh1,
         const float* __restrict__ W_ih2, const float* __restrict__ W_hh2,
         const float* __restrict__ b_ih2, const float* __restrict__ b_hh2,
         const float* __restrict__ W_out, const float* __restrict__ b_out,
         const float* __restrict__ h0in, const float* __restrict__ h1in,
         float* __restrict__ out, char* __restrict__ ws)
{
  extern __shared__ char smem[];
  unsigned short* wlds = (unsigned short*)smem;
  float* exch  = (float*)(smem + EXCH_OFF);
  unsigned short* sxu = (unsigned short*)(smem + SX_OFF);
  float* fmisc = (float*)(smem + FMISC_OFF);

  unsigned short* h0x = (unsigned short*)(ws + H0_OFF);
  unsigned short* h1x = (unsigned short*)(ws + H1_OFF);

  const int bid = blockIdx.x, tid = threadIdx.x;
  const int w = tid >> 6, l = tid & 63, l15 = l & 15, l4 = l >> 4;
  const int p_ = w >> 1;     // M half: rows 0-31 / 32-63 of the 64-row batch tile
  const int hh = w & 1;      // A: column half; B: gate role (r,in_ / z,hn)

  // group mapping, XCD-aware: blocks bid%8 in {2g,2g+1} form group g
  const int bt  = (bid & 7) >> 1;                 // group = batch tile
  const int sub = (bid >> 3) * 2 + (bid & 1);     // 0..47 within group
  const bool isA = (sub < 16);
  const int S = isA ? sub * 32 : (sub - 16) * 16;

  unsigned* pA = (unsigned*)(ws + CNT_OFF) + bt * 64;
  unsigned* pB = pA + 32;

  // ---------------- weight preload into LDS (bf16) ----------------
  if (isA) {
    for (int idx = tid; idx < 96 * 512; idx += 256) {
      int j = idx >> 9, kk = idx & 511;
      int h = j / 48, rr = j % 48, g = rr >> 4, c2 = rr & 15;
      int grow = g * 512 + S + h * 16 + c2;
      wlds[j * ASTRIDE + kk] = f2bf(W_hh1[grow * 512 + kk]);
    }
    if (tid < 96) {
      int j = tid, h = j / 48, rr = j % 48, g = rr >> 4, c2 = rr & 15;
      int grow = g * 512 + S + h * 16 + c2;
      fmisc[j]       = W_ih1[grow];
      fmisc[96 + j]  = b_ih1[grow];
      fmisc[192 + j] = b_hh1[grow];
    }
  } else {
    // region0: rows 0..15 = r-gate, 16..31 = z-gate; K=1024 = [W_ih2 | W_hh2]
    for (int idx = tid; idx < 32 * 1024; idx += 256) {
      int j = idx >> 10, kk = idx & 1023;
      int g = j >> 4, c2 = S + (j & 15);
      float v = (kk < 512) ? W_ih2[(g * 512 + c2) * 512 + kk]
                           : W_hh2[(g * 512 + c2) * 512 + kk - 512];
      wlds[j * B0STRIDE + kk] = f2bf(v);
    }
    // region1: in_ rows (W_ih2 n-gate); region2: hn rows (W_hh2 n-gate); K=512
    for (int idx = tid; idx < 16 * 512; idx += 256) {
      int j2 = idx >> 9, kk = idx & 511;
      wlds[R1BASE + j2 * BSTRIDE + kk] = f2bf(W_ih2[(1024 + S + j2) * 512 + kk]);
      wlds[R2BASE + j2 * BSTRIDE + kk] = f2bf(W_hh2[(1024 + S + j2) * 512 + kk]);
    }
    if (tid < 48) {
      int g = tid >> 4, c2 = S + (tid & 15);
      fmisc[tid]      = b_ih2[g * 512 + c2];
      fmisc[48 + tid] = b_hh2[g * 512 + c2];
    }
  }
  __syncthreads();

  // ---------------- per-thread constants / carries ----------------
  int rowb[2][4];
  int arowOff[2];
  #pragma unroll
  for (int mtl = 0; mtl < 2; ++mtl) {
    arowOff[mtl] = ((p_ * 2 + mtl) * 16 + l15) * 512;     // A-fragment row (lane&15-based)
    #pragma unroll
    for (int q = 0; q < 4; ++q)
      rowb[mtl][q] = bt * 64 + (p_ * 2 + mtl) * 16 + l4 * 4 + q;  // D row (reg-based)
  }

  float carry[2][4];
  #pragma unroll
  for (int mtl = 0; mtl < 2; ++mtl)
    #pragma unroll
    for (int q = 0; q < 4; ++q) carry[mtl][q] = 0.0f;
  if (isA) {
    int c = S + hh * 16 + l15;
    #pragma unroll
    for (int mtl = 0; mtl < 2; ++mtl)
      #pragma unroll
      for (int q = 0; q < 4; ++q) carry[mtl][q] = h0in[rowb[mtl][q] * 512 + c];
  } else if (hh == 1) {
    int c = S + l15;
    #pragma unroll
    for (int mtl = 0; mtl < 2; ++mtl)
      #pragma unroll
      for (int q = 0; q < 4; ++q) carry[mtl][q] = h1in[rowb[mtl][q] * 512 + c];
  }
  const float wout = (!isA && hh == 1) ? W_out[S + l15] : 0.0f;

  int dead = 0;   // only tid0's copy matters

  // wait until *c0 >= t0 && *c1 >= t1 (tid0 polls relaxed/sc1).
  // BACKOFF polling: one immediate fast-path check, then ~1.5K-cycle sleeps.
  auto block_wait = [&](unsigned* c0, unsigned t0, unsigned* c1, unsigned t1) {
    if (tid == 0 && !dead) {
      if (__hip_atomic_load(c0, __ATOMIC_RELAXED, __HIP_MEMORY_SCOPE_AGENT) < t0 ||
          __hip_atomic_load(c1, __ATOMIC_RELAXED, __HIP_MEMORY_SCOPE_AGENT) < t1) {
        int spins = 0;
        for (;;) {
          __builtin_amdgcn_s_sleep(24);   // backoff FIRST, then re-check
          if (__hip_atomic_load(c0, __ATOMIC_RELAXED, __HIP_MEMORY_SCOPE_AGENT) >= t0 &&
              __hip_atomic_load(c1, __ATOMIC_RELAXED, __HIP_MEMORY_SCOPE_AGENT) >= t1) break;
          if (++spins > 30000) { dead = 1; break; }   // bounded failure, no hang
        }
      }
    }
    __syncthreads();
  };
  // publisher: all state stores are sc1 write-through; drain them, then relaxed add
  auto block_publish = [&](unsigned* c) {
    asm volatile("s_waitcnt vmcnt(0)" ::: "memory");
    __syncthreads();
    if (tid == 0) __hip_atomic_fetch_add(c, 1u, __ATOMIC_RELAXED, __HIP_MEMORY_SCOPE_AGENT);
  };
  // coherent (IF-level, sc1) u64 store of repacked state
  auto st_coh = [&](unsigned short* p, unsigned long long v) {
    __hip_atomic_store((unsigned long long*)p, v, __ATOMIC_RELAXED, __HIP_MEMORY_SCOPE_AGENT);
  };

  if (isA) {
    // ============ cell-1 blocks: compute h0(k), k = 0..TN-1 ============
    for (int k = 0; k < TN; ++k) {
      // x column loads are flag-independent: issue before the wait
      float xv[2][4];
      #pragma unroll
      for (int mtl = 0; mtl < 2; ++mtl)
        #pragma unroll
        for (int q = 0; q < 4; ++q) xv[mtl][q] = x[rowb[mtl][q] * 2048 + k];

      block_wait(pA, 16u * (unsigned)k,
                 pB, (k >= 3) ? 32u * (unsigned)(k - 3) : 0u);

      f32x4 acc[2][3];
      #pragma unroll
      for (int mtl = 0; mtl < 2; ++mtl)
        #pragma unroll
        for (int g = 0; g < 3; ++g) acc[mtl][g] = f32x4{0.f, 0.f, 0.f, 0.f};

      const unsigned short* srcA = h0x + ((k + 3) & 3) * 131072 + bt * 32768; // h0(k-1)
      #pragma unroll 4
      for (int ks = 0; ks < 16; ++ks) {
        bf16x8 af[2];
        #pragma unroll
        for (int mtl = 0; mtl < 2; ++mtl)
          af[mtl] = ld_coh16(srcA + arowOff[mtl] + ks * 32 + l4 * 8);
        #pragma unroll
        for (int g = 0; g < 3; ++g) {
          bf16x8 bw = *(const bf16x8*)(wlds + (hh * 48 + g * 16 + l15) * ASTRIDE + ks * 32 + l4 * 8);
          #pragma unroll
          for (int mtl = 0; mtl < 2; ++mtl)
            acc[mtl][g] = __builtin_amdgcn_mfma_f32_16x16x32_bf16(af[mtl], bw, acc[mtl][g], 0, 0, 0);
        }
      }

      int cc = hh * 16 + l15;          // local column 0..31
      int jb = hh * 48 + l15;
      float wir = fmisc[jb],       wiz = fmisc[jb + 16],       win = fmisc[jb + 32];
      float bir = fmisc[96 + jb],  biz = fmisc[96 + jb + 16],  bin = fmisc[96 + jb + 32];
      float bhr = fmisc[192 + jb], bhz = fmisc[192 + jb + 16], bhn = fmisc[192 + jb + 32];
      #pragma unroll
      for (int mtl = 0; mtl < 2; ++mtl)
        #pragma unroll
        for (int q = 0; q < 4; ++q) {
          float rg = sigf(xv[mtl][q] * wir + bir + acc[mtl][0][q] + bhr);
          float zg = sigf(xv[mtl][q] * wiz + biz + acc[mtl][1][q] + bhz);
          float ng = tanhf_(xv[mtl][q] * win + bin + rg * (acc[mtl][2][q] + bhn));
          float hv = (1.0f - zg) * ng + zg * carry[mtl][q];
          carry[mtl][q] = hv;
          sxu[((p_ * 2 + mtl) * 16 + l4 * 4 + q) * 32 + cc] = f2bf(hv);  // repack
        }
      __syncthreads();
      {
        const unsigned long long* sxq = (const unsigned long long*)sxu;
        unsigned long long v0 = sxq[tid * 2], v1 = sxq[tid * 2 + 1];
        unsigned short* dsth = h0x + (k & 3) * 131072
                             + (bt * 64 + (tid >> 2)) * 512 + S + (tid & 3) * 8;
        st_coh(dsth, v0);
        st_coh(dsth + 4, v1);
      }
      block_publish(pA);
    }
  } else {
    // ============ cell-2 blocks: compute h1(j), j = 0..TN-1 ============
    // PHASE ORDER (R17): consume OLD data (h0(j), published a full tick ago by
    // the ahead-running A) first; the FRESH pB dependency's store-drain +
    // IF-visibility + straggler window hides under that work.
    for (int j = 0; j < TN; ++j) {
      f32x4 acc[2][2];
      #pragma unroll
      for (int mtl = 0; mtl < 2; ++mtl)
        #pragma unroll
        for (int g = 0; g < 2; ++g) acc[mtl][g] = f32x4{0.f, 0.f, 0.f, 0.f};

      // ---- phase 1: h0(j) half (K 0..511) -- needs pA >= 16(j+1) [usually instant] ----
      block_wait(pA, 16u * (unsigned)(j + 1), pA, 0u);

      const unsigned short* src0 = h0x + (j & 3) * 131072 + bt * 32768;       // h0(j)
      #pragma unroll 4
      for (int ks = 0; ks < 16; ++ks) {
        bf16x8 af[2];
        #pragma unroll
        for (int mtl = 0; mtl < 2; ++mtl)
          af[mtl] = ld_coh16(src0 + arowOff[mtl] + ks * 32 + l4 * 8);
        bf16x8 b0 = *(const bf16x8*)(wlds + (hh * 16 + l15) * B0STRIDE + ks * 32 + l4 * 8);
        #pragma unroll
        for (int mtl = 0; mtl < 2; ++mtl)
          acc[mtl][0] = __builtin_amdgcn_mfma_f32_16x16x32_bf16(af[mtl], b0, acc[mtl][0], 0, 0, 0);
        if (hh == 0) {
          bf16x8 b1 = *(const bf16x8*)(wlds + R1BASE + l15 * BSTRIDE + ks * 32 + l4 * 8);
          #pragma unroll
          for (int mtl = 0; mtl < 2; ++mtl)
            acc[mtl][1] = __builtin_amdgcn_mfma_f32_16x16x32_bf16(af[mtl], b1, acc[mtl][1], 0, 0, 0);
        }
      }

      // ---- phase 2: h1(j-1) half (K 512..1023) -- needs pB >= 32j (visibility hidden) ----
      block_wait(pB, 32u * (unsigned)j, pB, 0u);

      const unsigned short* src1 = h1x + ((j + 3) & 3) * 131072 + bt * 32768; // h1(j-1)
      #pragma unroll 4
      for (int ks = 16; ks < 32; ++ks) {
        int koff = (ks & 15) * 32;
        bf16x8 af[2];
        #pragma unroll
        for (int mtl = 0; mtl < 2; ++mtl)
          af[mtl] = ld_coh16(src1 + arowOff[mtl] + koff + l4 * 8);
        bf16x8 b0 = *(const bf16x8*)(wlds + (hh * 16 + l15) * B0STRIDE + ks * 32 + l4 * 8);
        #pragma unroll
        for (int mtl = 0; mtl < 2; ++mtl)
          acc[mtl][0] = __builtin_amdgcn_mfma_f32_16x16x32_bf16(af[mtl], b0, acc[mtl][0], 0, 0, 0);
        if (hh == 1) {
          bf16x8 b1 = *(const bf16x8*)(wlds + R2BASE + l15 * BSTRIDE + (ks - 16) * 32 + l4 * 8);
          #pragma unroll
          for (int mtl = 0; mtl < 2; ++mtl)
            acc[mtl][1] = __builtin_amdgcn_mfma_f32_16x16x32_bf16(af[mtl], b1, acc[mtl][1], 0, 0, 0);
        }
      }

      // exchange r/in_ (hh0) -> hh1 waves
      if (hh == 0) {
        #pragma unroll
        for (int mtl = 0; mtl < 2; ++mtl)
          #pragma unroll
          for (int qn = 0; qn < 2; ++qn)
            #pragma unroll
            for (int q = 0; q < 4; ++q)
              exch[((p_ * 2 + qn) * 32 + mtl * 16 + l4 * 4 + q) * 17 + l15] = acc[mtl][qn][q];
      }
      __syncthreads();
      if (hh == 1) {
        float bir = fmisc[l15],      biz = fmisc[16 + l15], bin = fmisc[32 + l15];
        float bhr = fmisc[48 + l15], bhz = fmisc[64 + l15], bhn = fmisc[80 + l15];
        #pragma unroll
        for (int mtl = 0; mtl < 2; ++mtl)
          #pragma unroll
          for (int q = 0; q < 4; ++q) {
            float rv = exch[((p_ * 2 + 0) * 32 + mtl * 16 + l4 * 4 + q) * 17 + l15];
            float iv = exch[((p_ * 2 + 1) * 32 + mtl * 16 + l4 * 4 + q) * 17 + l15];
            float rg = sigf(rv + bir + bhr);
            float zg = sigf(acc[mtl][0][q] + biz + bhz);
            float ng = tanhf_(iv + bin + rg * (acc[mtl][1][q] + bhn));
            float hv = (1.0f - zg) * ng + zg * carry[mtl][q];
            carry[mtl][q] = hv;
            sxu[((p_ * 2 + mtl) * 16 + l4 * 4 + q) * 16 + l15] = f2bf(hv);  // repack
            if (j == TN - 1) atomicAdd(&out[rowb[mtl][q]], hv * wout);      // projection
          }
      }
      __syncthreads();
      {
        const unsigned long long* sxq = (const unsigned long long*)sxu;
        unsigned long long v = sxq[tid];
        unsigned short* dsth = h1x + (j & 3) * 131072
                             + (bt * 64 + (tid >> 2)) * 512 + S + (tid & 3) * 4;
        st_coh(dsth, v);
      }
      block_publish(pB);
    }
  }
}

extern "C" void kernel_launch(void* const* d_in, const int* in_sizes, int n_in,
                              void* d_out, int out_size, void* d_ws, size_t ws_size,
                              hipStream_t stream) {
  const float* x     = (const float*)d_in[0];
  const float* h0in  = (const float*)d_in[1];
  const float* h1in  = (const float*)d_in[2];
  const float* W_ih1 = (const float*)d_in[3];
  const float* W_hh1 = (const float*)d_in[4];
  const float* b_ih1 = (const float*)d_in[5];
  const float* b_hh1 = (const float*)d_in[6];
  const float* W_ih2 = (const float*)d_in[7];
  const float* W_hh2 = (const float*)d_in[8];
  const float* b_ih2 = (const float*)d_in[9];
  const float* b_hh2 = (const float*)d_in[10];
  const float* W_out = (const float*)d_in[11];
  const float* b_out = (const float*)d_in[12];
  float* out = (float*)d_out;
  char* ws = (char*)d_ws;

  (void)in_sizes; (void)n_in; (void)out_size; (void)ws_size;

  hipFuncSetAttribute((const void*)gru_main,
                      hipFuncAttributeMaxDynamicSharedMemorySize, SMEM_BYTES);

  hipLaunchKernelGGL(gru_init, dim3(512), dim3(256), 0, stream,
                     h0in, h1in, b_out, out, ws);

  void* args[] = { (void*)&x,
                   (void*)&W_ih1, (void*)&W_hh1, (void*)&b_ih1, (void*)&b_hh1,
                   (void*)&W_ih2, (void*)&W_hh2, (void*)&b_ih2, (void*)&b_hh2,
                   (void*)&W_out, (void*)&b_out,
                   (void*)&h0in, (void*)&h1in,
                   (void*)&out, (void*)&ws };
  hipLaunchCooperativeKernel((const void*)gru_main, dim3(NBLK), dim3(256),
                             args, SMEM_BYTES, stream);
}